// Round 10
// baseline (946.891 us; speedup 1.0000x reference)
//
#include <hip/hip_runtime.h>
#include <hip/hip_bf16.h>

#define NN 50000      // nodes
#define NE 100000     // edges
#define NG 2500       // graphs
#define WW 128        // edge-mlp width
#define EPAD 100352   // 196 blocks * 512 edges (= 784 * 128)
#define KCH 264       // K chunks of 32: 8448 = 132 h-rows * 64 (128 hid + 1 bias + 3 zero)
#define GPB 4         // graphs per s2s block
#define SCAP 160      // max staged nodes per s2s block (4 graphs, avg 80)

typedef _Float16 h8 __attribute__((ext_vector_type(8)));
typedef _Float16 h4 __attribute__((ext_vector_type(4)));
typedef float    f4 __attribute__((ext_vector_type(4)));

#define GLOAD_LDS16(g, l) __builtin_amdgcn_global_load_lds( \
    (const __attribute__((address_space(1))) void*)(g),     \
    (__attribute__((address_space(3))) void*)(l), 16, 0, 0)

__device__ __forceinline__ float sigf(float x) { return 1.0f / (1.0f + __expf(-x)); }

// zero n4 float4's
__global__ void k_zero4(float4* __restrict__ p, int n4) {
    int i = blockIdx.x * 256 + threadIdx.x;
    if (i < n4) p[i] = make_float4(0.f, 0.f, 0.f, 0.f);
}

// dst[c*rows + r] = src[r*cols + c]
__global__ void k_transpose(float* dst, const float* src, int rows, int cols) {
    int idx = blockIdx.x * 256 + threadIdx.x;
    if (idx >= rows * cols) return;
    int r = idx / cols, c = idx % cols;
    dst[c * rows + r] = src[idx];
}

// s[n,o] = relu([x|z] @ lin0_w + b); also writes f16 copy
__global__ void k_lin0(const float* __restrict__ x, const float* __restrict__ z,
                       const float* __restrict__ w, const float* __restrict__ b,
                       float* __restrict__ s, _Float16* __restrict__ s16) {
    int idx = blockIdx.x * 256 + threadIdx.x;  // NN*64 exact
    int n = idx >> 6, o = idx & 63;
    float acc = b[o];
#pragma unroll
    for (int i = 0; i < 15; i++) acc += x[n * 15 + i] * w[i * 64 + o];
    acc += z[n] * w[15 * 64 + o];
    float r = fmaxf(acc, 0.0f);
    s[idx] = r;
    s16[idx] = (_Float16)r;
}

__global__ void k_deg(const int* __restrict__ dstI, float* __restrict__ deg) {
    int e = blockIdx.x * 256 + threadIdx.x;
    if (e < NE) atomicAdd(&deg[dstI[e]], 1.0f);
}

// gstart[g] = first node n with batch[n] >= g (batch sorted); gstart[NG] = NN
__global__ void k_gstart(const int* __restrict__ batch, int* __restrict__ gstart) {
    int n = blockIdx.x * 256 + threadIdx.x;
    if (n > NN) return;
    int b1 = (n < NN) ? batch[n] : NG;
    int b0 = (n == 0) ? -1 : batch[n - 1];
    for (int g = b0 + 1; g <= b1; g++) gstart[g] = n;
}

// edge MLP layer 1 fused with repack to f16 h4-groups:
// hidT4[hq][e][j] = hid[e][hq*4+j], hq = 0..32 (132 rows: 128 hid + bias(=1) + 3 zero)
__global__ void k_emlp_t(const float* __restrict__ ea, const float* __restrict__ w1,
                         const float* __restrict__ b1, _Float16* __restrict__ hidT4) {
    __shared__ _Float16 hl[132][64];
    int t = threadIdx.x;
    int e0 = blockIdx.x * 64;
    int e_l = t & 63, w = t >> 6;
    int e = e0 + e_l;
    float a0 = 0, a1 = 0, a2 = 0, a3 = 0, a4 = 0;
    if (e < NE) {
        a0 = ea[e * 5 + 0]; a1 = ea[e * 5 + 1]; a2 = ea[e * 5 + 2];
        a3 = ea[e * 5 + 3]; a4 = ea[e * 5 + 4];
    }
    for (int h = w * 32; h < w * 32 + 32; h++) {
        float acc = b1[h];
        acc += a0 * w1[0 * 128 + h] + a1 * w1[1 * 128 + h] + a2 * w1[2 * 128 + h]
             + a3 * w1[3 * 128 + h] + a4 * w1[4 * 128 + h];
        hl[h][e_l] = (_Float16)fmaxf(acc, 0.0f);
    }
    if (t < 64) hl[128][t] = (_Float16)1.0f;
    else if (t < 128) hl[129][t - 64] = (_Float16)0.0f;
    else if (t < 192) hl[130][t - 128] = (_Float16)0.0f;
    else hl[131][t - 192] = (_Float16)0.0f;
    __syncthreads();
#pragma unroll
    for (int it = 0; it < 9; it++) {
        int hq = it * 4 + w;          // 9*4 = 36 slots cover hq 0..32
        if (hq < 33) {
            h4 v = { hl[hq * 4 + 0][e_l], hl[hq * 4 + 1][e_l],
                     hl[hq * 4 + 2][e_l], hl[hq * 4 + 3][e_l] };
            *(h4*)(hidT4 + ((size_t)hq * EPAD + e0 + e_l) * 4) = v;
        }
    }
}

// Pre-arrange B = [w2 ; b2 ; 0] (shape [8448,64]) into MFMA-fragment order
__global__ void k_prep_B(const float* __restrict__ w2, const float* __restrict__ b2,
                         _Float16* __restrict__ Bp) {
    int g = blockIdx.x * 256 + threadIdx.x;   // KCH*4*64 = 67584 exact
    int l = g & 63, tt = (g >> 6) & 3, c = g >> 8;
    int n = tt * 16 + (l & 15);
    int kb = c * 32 + (l >> 4) * 8;
    h8 v;
#pragma unroll
    for (int j = 0; j < 8; j++) {
        int k = kb + j;
        float f = 0.0f;
        if (k < 8192) f = w2[(size_t)k * 64 + n];
        else if (k < 8256) f = b2[(k - 8192) * 64 + n];
        v[j] = (_Float16)f;
    }
    *((h8*)Bp + g) = v;
}

// Pre-arrange combine weights into MFMA B-fragment layout (f16)
__global__ void k_prep_W(const float* __restrict__ conv_root,
                         const float* __restrict__ gru_wi,
                         const float* __restrict__ gru_wh,
                         _Float16* __restrict__ Bw) {
    int g = blockIdx.x * 256 + threadIdx.x;   // 56*64 = 3584
    if (g >= 56 * 64) return;
    int l = g & 63, unit = g >> 6;
    int kb = ((unit & 1) * 32) + (l >> 4) * 8;
    h8 v;
    if (unit < 8) {
        int nt = unit >> 1;
        int n = nt * 16 + (l & 15);
#pragma unroll
        for (int j = 0; j < 8; j++) v[j] = (_Float16)conv_root[(kb + j) * 64 + n];
    } else if (unit < 32) {
        int nt = (unit - 8) >> 1;
        int o = nt * 16 + (l & 15);
#pragma unroll
        for (int j = 0; j < 8; j++) v[j] = (_Float16)gru_wi[o * 64 + kb + j];
    } else {
        int nt = (unit - 32) >> 1;
        int o = nt * 16 + (l & 15);
#pragma unroll
        for (int j = 0; j < 8; j++) v[j] = (_Float16)gru_wh[o * 64 + kb + j];
    }
    *((h8*)Bw + g) = v;
}

// Fused NNConv message. v10: 512 edges/block (8 waves, 512 thr) sharing one
// LDS-staged B stream. 196 blocks <= 256 CUs -> every block owns its CU
// (no 2-block serialization, which set v6's makespan); per-phase fixed cost
// (stage issue + drain + barrier) amortized over 2x the MFMA work; B panel
// streamed once per 512 edges -> 211 MB L2 traffic. Per-wave code identical
// to the 3-round-verified v6 structure (K-step 128, 2x16KB double buffer,
// stage-before-compute).
__global__ __launch_bounds__(512, 2) void k_fused(
        const _Float16* __restrict__ s16, const _Float16* __restrict__ hidT4,
        const _Float16* __restrict__ Bp, const int* __restrict__ srcI,
        const int* __restrict__ dstI, float* __restrict__ aggr) {
    __shared__ uint4 Bl[2][1024];         // 2 x 16 KB (K-step 128)
    int t = threadIdx.x, w = t >> 6, lane = t & 63;
    int m = lane & 15, q = lane >> 4;
    int ew0 = blockIdx.x * 512 + w * 64;  // wave's 64 edges

    h8 sA[4][2];
#pragma unroll
    for (int mt = 0; mt < 4; mt++) {
        int e = ew0 + mt * 16 + m;
        int src = (e < NE) ? srcI[e] : 0;
        const _Float16* sp = s16 + (size_t)src * 64;
        sA[mt][0] = *(const h8*)(sp + q * 8);
        sA[mt][1] = *(const h8*)(sp + 32 + q * 8);
    }
    f4 acc[4][4];
#pragma unroll
    for (int mt = 0; mt < 4; mt++)
#pragma unroll
        for (int nt = 0; nt < 4; nt++) acc[mt][nt] = (f4){0.f, 0.f, 0.f, 0.f};

    const h4* hT = (const h4*)hidT4;
    h4 hfA[4], hfB[4];
#pragma unroll
    for (int mt = 0; mt < 4; mt++)
        hfA[mt] = hT[(size_t)0 * EPAD + ew0 + mt * 16 + m];

    // prologue: stage K-step 0 -> buf 0 (1024 uint4 by 512 threads)
    {
        const uint4* bs = (const uint4*)Bp;
#pragma unroll
        for (int r = 0; r < 2; r++) GLOAD_LDS16(bs + r * 512 + t, &Bl[0][r * 512 + t]);
    }
    __syncthreads();

#define COMPUTE_STEP(BUF, HH)                                                  \
    _Pragma("unroll")                                                          \
    for (int c2 = 0; c2 < 4; c2++) {                                           \
        h8 b0 = *(const h8*)&Bl[BUF][(c2 * 4 + 0) * 64 + lane];                \
        h8 b1 = *(const h8*)&Bl[BUF][(c2 * 4 + 1) * 64 + lane];                \
        h8 b2 = *(const h8*)&Bl[BUF][(c2 * 4 + 2) * 64 + lane];                \
        h8 b3 = *(const h8*)&Bl[BUF][(c2 * 4 + 3) * 64 + lane];                \
        _Pragma("unroll")                                                      \
        for (int mt = 0; mt < 4; mt++) {                                       \
            h8 a = sA[mt][c2 & 1] * hfA[mt][(HH) + (c2 >> 1)];                 \
            acc[mt][0] = __builtin_amdgcn_mfma_f32_16x16x32_f16(a, b0, acc[mt][0], 0, 0, 0); \
            acc[mt][1] = __builtin_amdgcn_mfma_f32_16x16x32_f16(a, b1, acc[mt][1], 0, 0, 0); \
            acc[mt][2] = __builtin_amdgcn_mfma_f32_16x16x32_f16(a, b2, acc[mt][2], 0, 0, 0); \
            acc[mt][3] = __builtin_amdgcn_mfma_f32_16x16x32_f16(a, b3, acc[mt][3], 0, 0, 0); \
        }                                                                      \
    }

    for (int tt = 0; tt < 33; tt++) {
        // ---- phase A (st = 2tt): stage st+1 -> buf1; compute buf0
        {
            const uint4* bs = (const uint4*)Bp + (size_t)(2 * tt + 1) * 1024;
#pragma unroll
            for (int r = 0; r < 2; r++) GLOAD_LDS16(bs + r * 512 + t, &Bl[1][r * 512 + t]);
        }
        {   // prefetch next h4 group (tt+1; group 33 is the slack row)
#pragma unroll
            for (int mt = 0; mt < 4; mt++)
                hfB[mt] = hT[(size_t)(tt + 1) * EPAD + ew0 + mt * 16 + m];
        }
        COMPUTE_STEP(0, 0)
        __syncthreads();

        // ---- phase B (st = 2tt+1): stage st+2 -> buf0; compute buf1
        if (tt + 1 < 33) {
            const uint4* bs = (const uint4*)Bp + (size_t)(2 * tt + 2) * 1024;
#pragma unroll
            for (int r = 0; r < 2; r++) GLOAD_LDS16(bs + r * 512 + t, &Bl[0][r * 512 + t]);
        }
        COMPUTE_STEP(1, 2)
#pragma unroll
        for (int mt = 0; mt < 4; mt++) hfA[mt] = hfB[mt];
        __syncthreads();
    }
#undef COMPUTE_STEP

    // epilogue: C/D layout col=lane&15, row=q*4+reg
#pragma unroll
    for (int mt = 0; mt < 4; mt++) {
        int eb = ew0 + mt * 16 + q * 4;
#pragma unroll
        for (int r = 0; r < 4; r++) {
            int e = eb + r;
            if (e < NE) {
                int d = dstI[e];
                float* ap = aggr + (size_t)d * 64 + m;
                atomicAdd(ap + 0,  acc[mt][0][r]);
                atomicAdd(ap + 16, acc[mt][1][r]);
                atomicAdd(ap + 32, acc[mt][2][r]);
                atomicAdd(ap + 48, acc[mt][3][r]);
            }
        }
    }
}

// MFMA NNConv-root + GRU combine. Block=256 (4 waves), 64 nodes/block.
// Reads aggr AND zeroes it (owner thread only) -> removes per-step zero launch.
__global__ __launch_bounds__(256) void k_combine2(
        float* __restrict__ s, _Float16* __restrict__ s16,
        float* __restrict__ aggr, const float* __restrict__ deg,
        const _Float16* __restrict__ Bw, const float* __restrict__ cb,
        const float* __restrict__ bi, const float* __restrict__ bh) {
    __shared__ _Float16 ml[4][16][72];
    int t = threadIdx.x, w = t >> 6, lane = t & 63;
    int m = lane & 15, q = lane >> 4;
    int nb = blockIdx.x * 64 + w * 16;

    h8 sa0, sa1;
    {
        int node = nb + m; if (node >= NN) node = NN - 1;
        const _Float16* sp = s16 + (size_t)node * 64;
        sa0 = *(const h8*)(sp + q * 8);
        sa1 = *(const h8*)(sp + 32 + q * 8);
    }
    const h8* BW = (const h8*)Bw;

    f4 X[4], GH[12];
#pragma unroll
    for (int nt = 0; nt < 4; nt++) {
        X[nt] = (f4){0.f, 0.f, 0.f, 0.f};
        X[nt] = __builtin_amdgcn_mfma_f32_16x16x32_f16(sa0, BW[(nt * 2 + 0) * 64 + lane], X[nt], 0, 0, 0);
        X[nt] = __builtin_amdgcn_mfma_f32_16x16x32_f16(sa1, BW[(nt * 2 + 1) * 64 + lane], X[nt], 0, 0, 0);
    }
#pragma unroll
    for (int nt = 0; nt < 12; nt++) {
        GH[nt] = (f4){0.f, 0.f, 0.f, 0.f};
        GH[nt] = __builtin_amdgcn_mfma_f32_16x16x32_f16(sa0, BW[(32 + nt * 2 + 0) * 64 + lane], GH[nt], 0, 0, 0);
        GH[nt] = __builtin_amdgcn_mfma_f32_16x16x32_f16(sa1, BW[(32 + nt * 2 + 1) * 64 + lane], GH[nt], 0, 0, 0);
    }
#pragma unroll
    for (int r = 0; r < 4; r++) {
        int node = nb + q * 4 + r;
        bool ok = node < NN;
        int nc = ok ? node : NN - 1;
        float dn = fmaxf(deg[nc], 1.0f);
#pragma unroll
        for (int nt = 0; nt < 4; nt++) {
            int o = nt * 16 + m;
            size_t ai = (size_t)nc * 64 + o;
            float av = aggr[ai];
            if (ok) aggr[ai] = 0.0f;   // only the owning thread zeroes (no race)
            float mv = X[nt][r] + av / dn + cb[o];
            ml[w][q * 4 + r][o] = (_Float16)fmaxf(mv, 0.0f);
        }
    }
    __syncthreads();
    h8 ma0 = *(const h8*)&ml[w][m][q * 8];
    h8 ma1 = *(const h8*)&ml[w][m][32 + q * 8];

    f4 GI[12];
#pragma unroll
    for (int nt = 0; nt < 12; nt++) {
        GI[nt] = (f4){0.f, 0.f, 0.f, 0.f};
        GI[nt] = __builtin_amdgcn_mfma_f32_16x16x32_f16(ma0, BW[(8 + nt * 2 + 0) * 64 + lane], GI[nt], 0, 0, 0);
        GI[nt] = __builtin_amdgcn_mfma_f32_16x16x32_f16(ma1, BW[(8 + nt * 2 + 1) * 64 + lane], GI[nt], 0, 0, 0);
    }
#pragma unroll
    for (int og = 0; og < 4; og++) {
        int o = og * 16 + m;
        float bir = bi[o],       bhr = bh[o];
        float biz = bi[64 + o],  bhz = bh[64 + o];
        float bin = bi[128 + o], bhn = bh[128 + o];
#pragma unroll
        for (int r = 0; r < 4; r++) {
            int node = nb + q * 4 + r;
            if (node >= NN) continue;
            float rr = sigf(GI[og][r] + bir + GH[og][r] + bhr);
            float zz = sigf(GI[4 + og][r] + biz + GH[4 + og][r] + bhz);
            float ng = tanhf(GI[8 + og][r] + bin + rr * (GH[8 + og][r] + bhn));
            float hold = s[(size_t)node * 64 + o];
            float hnew = (1.0f - zz) * ng + zz * hold;
            s[(size_t)node * 64 + o] = hnew;
            s16[(size_t)node * 64 + o] = (_Float16)hnew;
        }
    }
}

// Set2Set v2: GPB=4 graphs per block (grid 625). Wave w owns graph g0+w.
// Gate matmul shares each weight load across 4 graphs; s rows staged in LDS
// once; pooling lane-per-node with butterfly max/sum + online-softmax merge.
__global__ __launch_bounds__(256) void k_s2s5(
        const float* __restrict__ LiT, const float* __restrict__ LhT,
        const float* __restrict__ bi, const float* __restrict__ bh,
        const float* __restrict__ s, const int* __restrict__ gstart,
        float* __restrict__ e_v,
        const float* __restrict__ w1, const float* __restrict__ b1,
        const float* __restrict__ w2, const float* __restrict__ b2,
        float* __restrict__ y) {
    __shared__ float sl[SCAP][65];
    __shared__ float qs[GPB][128], hv[GPB][64], cv[GPB][64], gg[GPB][256];
    __shared__ int ginfo[GPB + 1];
    int t = threadIdx.x, w = t >> 6, o = t & 63;
    int g0 = blockIdx.x * GPB;
    if (t <= GPB) ginfo[t] = gstart[g0 + t];
    if (t < 128) {
#pragma unroll
        for (int gr = 0; gr < GPB; gr++) qs[gr][t] = 0.0f;
    }
    if (t < 64) {
#pragma unroll
        for (int gr = 0; gr < GPB; gr++) { hv[gr][t] = 0.0f; cv[gr][t] = 0.0f; }
    }
    __syncthreads();
    int n00 = ginfo[0];
    int cnt4 = ginfo[GPB] - n00;
    bool staged = (cnt4 <= SCAP);
    if (staged) {
        for (int idx = t; idx < cnt4 * 16; idx += 256) {
            int node = idx >> 4, c4 = (idx & 15) * 4;
            float4 v = *(const float4*)&s[(size_t)(n00 + node) * 64 + c4];
            sl[node][c4 + 0] = v.x; sl[node][c4 + 1] = v.y;
            sl[node][c4 + 2] = v.z; sl[node][c4 + 3] = v.w;
        }
    }
    __syncthreads();
    int myn0 = ginfo[w] - n00, myn1 = ginfo[w + 1] - n00;

    for (int it = 0; it < 5; it++) {
        float a0 = bi[t] + bh[t], a1 = a0, a2 = a0, a3 = a0;
        for (int k = 0; k < 128; k++) {
            float wv = LiT[k * 256 + t];
            a0 += qs[0][k] * wv; a1 += qs[1][k] * wv;
            a2 += qs[2][k] * wv; a3 += qs[3][k] * wv;
        }
        for (int k = 0; k < 64; k++) {
            float wv = LhT[k * 256 + t];
            a0 += hv[0][k] * wv; a1 += hv[1][k] * wv;
            a2 += hv[2][k] * wv; a3 += hv[3][k] * wv;
        }
        gg[0][t] = a0; gg[1][t] = a1; gg[2][t] = a2; gg[3][t] = a3;
        __syncthreads();
        {
            float c_new = sigf(gg[w][64 + o]) * cv[w][o] + sigf(gg[w][o]) * tanhf(gg[w][128 + o]);
            cv[w][o] = c_new;
            float hq = sigf(gg[w][192 + o]) * tanhf(c_new);
            hv[w][o] = hq;
            qs[w][o] = hq;
            float m = -3.4e38f, l = 0.0f, r = 0.0f;
            if (staged) {
                for (int c0 = myn0; c0 < myn1; c0 += 64) {
                    int nn = myn1 - c0; if (nn > 64) nn = 64;
                    float e = -3.4e38f;
                    if (o < nn) {
                        const float* row = &sl[c0 + o][0];
                        float acc = 0.0f;
                        for (int k = 0; k < 64; k++) acc += row[k] * qs[w][k];
                        e = acc;
                    }
                    float cm = e;
#pragma unroll
                    for (int off = 32; off; off >>= 1) cm = fmaxf(cm, __shfl_xor(cm, off, 64));
                    float mn = fmaxf(m, cm);
                    float a = (o < nn) ? __expf(e - mn) : 0.0f;
                    float csum = a;
#pragma unroll
                    for (int off = 32; off; off >>= 1) csum += __shfl_xor(csum, off, 64);
                    float scale = (m > -3.0e38f) ? __expf(m - mn) : 0.0f;
                    l = l * scale + csum;
                    r = r * scale;
                    for (int j = 0; j < nn; j++) {
                        float aj = __shfl(a, j, 64);
                        r += aj * sl[c0 + j][o];
                    }
                    m = mn;
                }
            } else {
                int an0 = myn0 + n00, an1 = myn1 + n00;
                float mx = -3.4e38f;
                for (int n = an0; n < an1; n++) {
                    float v = s[(size_t)n * 64 + o] * hq;
#pragma unroll
                    for (int off = 32; off; off >>= 1) v += __shfl_xor(v, off, 64);
                    if (o == 0) e_v[n] = v;
                    mx = fmaxf(mx, v);
                }
                float asum = 0.0f, rp = 0.0f;
                for (int n = an0; n < an1; n++) {
                    float a = __expf(e_v[n] - mx);
                    asum += a;
                    rp += a * s[(size_t)n * 64 + o];
                }
                l = asum; r = rp;
            }
            qs[w][64 + o] = r / (l + 1e-16f);
        }
        __syncthreads();
    }

    {
        float acc = b1[o];
        for (int k = 0; k < 128; k++) acc += qs[w][k] * w1[k * 64 + o];
        float hid = fmaxf(acc, 0.0f) * w2[o];
#pragma unroll
        for (int off = 32; off; off >>= 1) hid += __shfl_down(hid, off, 64);
        if (o == 0) y[g0 + w] = hid + b2[0];
    }
}

static inline void zero_f(float* p, size_t nfloats, hipStream_t stream) {
    int n4 = (int)(nfloats / 4);
    k_zero4<<<(n4 + 255) / 256, 256, 0, stream>>>((float4*)p, n4);
}

extern "C" void kernel_launch(void* const* d_in, const int* in_sizes, int n_in,
                              void* d_out, int out_size, void* d_ws, size_t ws_size,
                              hipStream_t stream) {
    const float* x       = (const float*)d_in[0];
    const float* z       = (const float*)d_in[1];
    const float* ea      = (const float*)d_in[2];
    const float* lin0_w  = (const float*)d_in[3];
    const float* lin0_b  = (const float*)d_in[4];
    const float* emlp_w1 = (const float*)d_in[5];
    const float* emlp_b1 = (const float*)d_in[6];
    const float* emlp_w2 = (const float*)d_in[7];
    const float* emlp_b2 = (const float*)d_in[8];
    const float* conv_r  = (const float*)d_in[9];
    const float* conv_b  = (const float*)d_in[10];
    const float* gru_wi  = (const float*)d_in[11];
    const float* gru_wh  = (const float*)d_in[12];
    const float* gru_bi  = (const float*)d_in[13];
    const float* gru_bh  = (const float*)d_in[14];
    const float* lstm_wi = (const float*)d_in[15];
    const float* lstm_wh = (const float*)d_in[16];
    const float* lstm_bi = (const float*)d_in[17];
    const float* lstm_bh = (const float*)d_in[18];
    const float* lin1_w  = (const float*)d_in[19];
    const float* lin1_b  = (const float*)d_in[20];
    const float* lin2_w  = (const float*)d_in[21];
    const float* lin2_b  = (const float*)d_in[22];
    const int* eidx      = (const int*)d_in[23];
    const int* batch     = (const int*)d_in[24];
    const int* srcI = eidx;
    const int* dstI = eidx + NE;
    float* y = (float*)d_out;

    char* w = (char*)d_ws;
    size_t off = 0;
    auto alloc = [&](size_t bytes) -> void* {
        void* p = w + off;
        off += (bytes + 255) & ~(size_t)255;
        return p;
    };
    float* s      = (float*)alloc((size_t)NN * 64 * 4);
    float* aggr   = (float*)alloc((size_t)NN * 64 * 4);
    float* deg    = (float*)alloc((size_t)NN * 4);
    float* e_v    = (float*)alloc((size_t)NN * 4);
    float* LiT    = (float*)alloc(256 * 128 * 4);
    float* LhT    = (float*)alloc(256 * 64 * 4);
    int*   gstart = (int*)alloc((size_t)(NG + 1) * 4);
    _Float16* s16 = (_Float16*)alloc((size_t)NN * 64 * 2);
    _Float16* hidT= (_Float16*)alloc((size_t)34 * EPAD * 4 * 2);  // 33 groups + 1 slack
    _Float16* Bp  = (_Float16*)alloc((size_t)KCH * 4 * 64 * 8 * 2);
    _Float16* Bw  = (_Float16*)alloc((size_t)56 * 64 * 8 * 2);
    (void)ws_size;  // ~60 MB total, well under proven capacity

    // weight prep
    k_transpose<<<(256 * 128 + 255) / 256, 256, 0, stream>>>(LiT, lstm_wi, 256, 128);
    k_transpose<<<(256 * 64 + 255) / 256, 256, 0, stream>>>(LhT, lstm_wh, 256, 64);
    k_prep_W<<<14, 256, 0, stream>>>(conv_r, gru_wi, gru_wh, Bw);

    // node embedding (+f16), degree, graph ranges, edge-MLP (-> hidT4), B prep
    k_lin0<<<NN * 64 / 256, 256, 0, stream>>>(x, z, lin0_w, lin0_b, s, s16);
    zero_f(deg, NN, stream);
    k_deg<<<(NE + 255) / 256, 256, 0, stream>>>(dstI, deg);
    k_gstart<<<(NN + 256) / 256, 256, 0, stream>>>(batch, gstart);
    k_emlp_t<<<EPAD / 64, 256, 0, stream>>>(ea, emlp_w1, emlp_b1, hidT);
    k_prep_B<<<KCH * 4 * 64 / 256, 256, 0, stream>>>(emlp_w2, emlp_b2, Bp);
    zero_f(aggr, (size_t)NN * 64, stream);   // once; combine2 re-zeroes each step

    // 5 message-passing + GRU steps (k_fused: 196 blocks x 512 thr, 512 edges/block)
    for (int step = 0; step < 5; step++) {
        k_fused<<<EPAD / 512, 512, 0, stream>>>(s16, hidT, Bp, srcI, dstI, aggr);
        k_combine2<<<(NN + 63) / 64, 256, 0, stream>>>(s, s16, aggr, deg, Bw,
                                                       conv_b, gru_bi, gru_bh);
    }

    // Set2Set (5 iterations, 4 graphs/block) + output head: one launch
    k_s2s5<<<NG / GPB, 256, 0, stream>>>(LiT, LhT, lstm_bi, lstm_bh, s, gstart, e_v,
                                         lin1_w, lin1_b, lin2_w, lin2_b, y);
}

// Round 11
// 884.522 us; speedup vs baseline: 1.0705x; 1.0705x over previous
//
#include <hip/hip_runtime.h>
#include <hip/hip_bf16.h>

#define NN 50000      // nodes
#define NE 100000     // edges
#define NG 2500       // graphs
#define WW 128        // edge-mlp width
#define EPAD 100096   // 391 blocks * 256 edges (= 782 * 128)
#define KCH 264       // K chunks of 32: 8448 = 132 h-rows * 64 (128 hid + 1 bias + 3 zero)
#define GPB 4         // graphs per s2s block
#define SCAP 160      // max staged nodes per s2s block (4 graphs, avg 80)

// mega-prologue block partition (cumulative ranges)
#define NBL0 12500    // lin0: NN*64/256
#define NBEM 1564     // emlp_t: EPAD/64
#define NBPB 264      // prep_B: KCH*4*64/256
#define NBPW 14       // prep_W
#define NBT1 128      // transpose LiT: 256*128/256
#define NBT2 64       // transpose LhT: 256*64/256
#define NBGS 196      // gstart: ceil((NN+1)/256)
#define NBZ  3174     // zero aggr+deg: ceil(NN*65/4/256)

typedef _Float16 h8 __attribute__((ext_vector_type(8)));
typedef _Float16 h4 __attribute__((ext_vector_type(4)));
typedef float    f4 __attribute__((ext_vector_type(4)));

#define GLOAD_LDS16(g, l) __builtin_amdgcn_global_load_lds( \
    (const __attribute__((address_space(1))) void*)(g),     \
    (__attribute__((address_space(3))) void*)(l), 16, 0, 0)

__device__ __forceinline__ float sigf(float x) { return 1.0f / (1.0f + __expf(-x)); }

// ---- mega-prologue: lin0 | emlp_t | prep_B | prep_W | transposes | gstart | zero
// All parts are mutually independent; one dispatch fills the machine instead of
// 8 serialized small launches.
__global__ __launch_bounds__(256) void k_prologue(
        const float* __restrict__ x, const float* __restrict__ z,
        const float* __restrict__ lin0_w, const float* __restrict__ lin0_b,
        float* __restrict__ s, _Float16* __restrict__ s16,
        const float* __restrict__ ea, const float* __restrict__ w1,
        const float* __restrict__ b1, _Float16* __restrict__ hidT4,
        const float* __restrict__ w2, const float* __restrict__ b2,
        _Float16* __restrict__ Bp,
        const float* __restrict__ conv_root, const float* __restrict__ gru_wi,
        const float* __restrict__ gru_wh, _Float16* __restrict__ Bw,
        const float* __restrict__ lstm_wi, const float* __restrict__ lstm_wh,
        float* __restrict__ LiT, float* __restrict__ LhT,
        const int* __restrict__ batch, int* __restrict__ gstart,
        float4* __restrict__ zbase) {
    __shared__ _Float16 hl[132][64];
    int bx = blockIdx.x, t = threadIdx.x;

    if (bx < NBL0) {
        // ---- lin0: s[n,o] = relu([x|z] @ lin0_w + b), + f16 copy
        int idx = bx * 256 + t;
        int n = idx >> 6, o = idx & 63;
        float acc = lin0_b[o];
#pragma unroll
        for (int i = 0; i < 15; i++) acc += x[n * 15 + i] * lin0_w[i * 64 + o];
        acc += z[n] * lin0_w[15 * 64 + o];
        float r = fmaxf(acc, 0.0f);
        s[idx] = r;
        s16[idx] = (_Float16)r;
        return;
    }
    bx -= NBL0;
    if (bx < NBEM) {
        // ---- edge MLP layer 1 + repack to h4 groups
        int e0 = bx * 64;
        int e_l = t & 63, w = t >> 6;
        int e = e0 + e_l;
        float a0 = 0, a1 = 0, a2 = 0, a3 = 0, a4 = 0;
        if (e < NE) {
            a0 = ea[e * 5 + 0]; a1 = ea[e * 5 + 1]; a2 = ea[e * 5 + 2];
            a3 = ea[e * 5 + 3]; a4 = ea[e * 5 + 4];
        }
        for (int h = w * 32; h < w * 32 + 32; h++) {
            float acc = b1[h];
            acc += a0 * w1[0 * 128 + h] + a1 * w1[1 * 128 + h] + a2 * w1[2 * 128 + h]
                 + a3 * w1[3 * 128 + h] + a4 * w1[4 * 128 + h];
            hl[h][e_l] = (_Float16)fmaxf(acc, 0.0f);
        }
        if (t < 64) hl[128][t] = (_Float16)1.0f;
        else if (t < 128) hl[129][t - 64] = (_Float16)0.0f;
        else if (t < 192) hl[130][t - 128] = (_Float16)0.0f;
        else hl[131][t - 192] = (_Float16)0.0f;
        __syncthreads();
#pragma unroll
        for (int it = 0; it < 9; it++) {
            int hq = it * 4 + w;
            if (hq < 33) {
                h4 v = { hl[hq * 4 + 0][e_l], hl[hq * 4 + 1][e_l],
                         hl[hq * 4 + 2][e_l], hl[hq * 4 + 3][e_l] };
                *(h4*)(hidT4 + ((size_t)hq * EPAD + e0 + e_l) * 4) = v;
            }
        }
        return;
    }
    bx -= NBEM;
    if (bx < NBPB) {
        // ---- prep_B: [w2 ; b2 ; 0] into MFMA-fragment order
        int g = bx * 256 + t;
        int l = g & 63, tt = (g >> 6) & 3, c = g >> 8;
        int n = tt * 16 + (l & 15);
        int kb = c * 32 + (l >> 4) * 8;
        h8 v;
#pragma unroll
        for (int j = 0; j < 8; j++) {
            int k = kb + j;
            float f = 0.0f;
            if (k < 8192) f = w2[(size_t)k * 64 + n];
            else if (k < 8256) f = b2[(k - 8192) * 64 + n];
            v[j] = (_Float16)f;
        }
        *((h8*)Bp + g) = v;
        return;
    }
    bx -= NBPB;
    if (bx < NBPW) {
        // ---- prep_W: combine weights into MFMA B-fragment layout
        int g = bx * 256 + t;
        if (g >= 56 * 64) return;
        int l = g & 63, unit = g >> 6;
        int kb = ((unit & 1) * 32) + (l >> 4) * 8;
        h8 v;
        if (unit < 8) {
            int nt = unit >> 1;
            int n = nt * 16 + (l & 15);
#pragma unroll
            for (int j = 0; j < 8; j++) v[j] = (_Float16)conv_root[(kb + j) * 64 + n];
        } else if (unit < 32) {
            int nt = (unit - 8) >> 1;
            int o = nt * 16 + (l & 15);
#pragma unroll
            for (int j = 0; j < 8; j++) v[j] = (_Float16)gru_wi[o * 64 + kb + j];
        } else {
            int nt = (unit - 32) >> 1;
            int o = nt * 16 + (l & 15);
#pragma unroll
            for (int j = 0; j < 8; j++) v[j] = (_Float16)gru_wh[o * 64 + kb + j];
        }
        *((h8*)Bw + g) = v;
        return;
    }
    bx -= NBPW;
    if (bx < NBT1) {
        // ---- LiT[c*256+r] = lstm_wi[r*128+c]  (rows=256, cols=128)
        int idx = bx * 256 + t;
        int r = idx / 128, c = idx % 128;
        LiT[c * 256 + r] = lstm_wi[idx];
        return;
    }
    bx -= NBT1;
    if (bx < NBT2) {
        // ---- LhT[c*256+r] = lstm_wh[r*64+c]  (rows=256, cols=64)
        int idx = bx * 256 + t;
        int r = idx / 64, c = idx % 64;
        LhT[c * 256 + r] = lstm_wh[idx];
        return;
    }
    bx -= NBT2;
    if (bx < NBGS) {
        // ---- gstart
        int n = bx * 256 + t;
        if (n > NN) return;
        int b1v = (n < NN) ? batch[n] : NG;
        int b0v = (n == 0) ? -1 : batch[n - 1];
        for (int g = b0v + 1; g <= b1v; g++) gstart[g] = n;
        return;
    }
    bx -= NBGS;
    {
        // ---- zero aggr+deg (contiguous NN*65 floats = 812500 float4)
        int i = bx * 256 + t;
        if (i < (NN * 65 / 4)) zbase[i] = make_float4(0.f, 0.f, 0.f, 0.f);
    }
}

__global__ void k_deg(const int* __restrict__ dstI, float* __restrict__ deg) {
    int e = blockIdx.x * 256 + threadIdx.x;
    if (e < NE) atomicAdd(&deg[dstI[e]], 1.0f);
}

// Fused NNConv message (v6 config — best measured across 5 geometry variants:
// 108.5-110 us, ~990 TF = the plain-HIP 2-barrier structural ceiling).
// 256 edges/block share one LDS-staged B stream; K-step 128 double-buffered;
// stage-before-compute so the barrier drain lands after the MFMA phase.
__global__ __launch_bounds__(256, 3) void k_fused(
        const _Float16* __restrict__ s16, const _Float16* __restrict__ hidT4,
        const _Float16* __restrict__ Bp, const int* __restrict__ srcI,
        const int* __restrict__ dstI, float* __restrict__ aggr) {
    __shared__ uint4 Bl[2][1024];         // 2 x 16 KB (K-step 128)
    int t = threadIdx.x, w = t >> 6, lane = t & 63;
    int m = lane & 15, q = lane >> 4;
    int ew0 = blockIdx.x * 256 + w * 64;  // wave's 64 edges

    h8 sA[4][2];
#pragma unroll
    for (int mt = 0; mt < 4; mt++) {
        int e = ew0 + mt * 16 + m;
        int src = (e < NE) ? srcI[e] : 0;
        const _Float16* sp = s16 + (size_t)src * 64;
        sA[mt][0] = *(const h8*)(sp + q * 8);
        sA[mt][1] = *(const h8*)(sp + 32 + q * 8);
    }
    f4 acc[4][4];
#pragma unroll
    for (int mt = 0; mt < 4; mt++)
#pragma unroll
        for (int nt = 0; nt < 4; nt++) acc[mt][nt] = (f4){0.f, 0.f, 0.f, 0.f};

    const h4* hT = (const h4*)hidT4;
    h4 hfA[4], hfB[4];
#pragma unroll
    for (int mt = 0; mt < 4; mt++)
        hfA[mt] = hT[(size_t)0 * EPAD + ew0 + mt * 16 + m];

    {
        const uint4* bs = (const uint4*)Bp;
#pragma unroll
        for (int r = 0; r < 4; r++) GLOAD_LDS16(bs + r * 256 + t, &Bl[0][r * 256 + t]);
    }
    __syncthreads();

#define COMPUTE_STEP(BUF, HH)                                                  \
    _Pragma("unroll")                                                          \
    for (int c2 = 0; c2 < 4; c2++) {                                           \
        h8 b0 = *(const h8*)&Bl[BUF][(c2 * 4 + 0) * 64 + lane];                \
        h8 b1 = *(const h8*)&Bl[BUF][(c2 * 4 + 1) * 64 + lane];                \
        h8 b2 = *(const h8*)&Bl[BUF][(c2 * 4 + 2) * 64 + lane];                \
        h8 b3 = *(const h8*)&Bl[BUF][(c2 * 4 + 3) * 64 + lane];                \
        _Pragma("unroll")                                                      \
        for (int mt = 0; mt < 4; mt++) {                                       \
            h8 a = sA[mt][c2 & 1] * hfA[mt][(HH) + (c2 >> 1)];                 \
            acc[mt][0] = __builtin_amdgcn_mfma_f32_16x16x32_f16(a, b0, acc[mt][0], 0, 0, 0); \
            acc[mt][1] = __builtin_amdgcn_mfma_f32_16x16x32_f16(a, b1, acc[mt][1], 0, 0, 0); \
            acc[mt][2] = __builtin_amdgcn_mfma_f32_16x16x32_f16(a, b2, acc[mt][2], 0, 0, 0); \
            acc[mt][3] = __builtin_amdgcn_mfma_f32_16x16x32_f16(a, b3, acc[mt][3], 0, 0, 0); \
        }                                                                      \
    }

    for (int tt = 0; tt < 33; tt++) {
        {
            const uint4* bs = (const uint4*)Bp + (size_t)(2 * tt + 1) * 1024;
#pragma unroll
            for (int r = 0; r < 4; r++) GLOAD_LDS16(bs + r * 256 + t, &Bl[1][r * 256 + t]);
        }
        {
#pragma unroll
            for (int mt = 0; mt < 4; mt++)
                hfB[mt] = hT[(size_t)(tt + 1) * EPAD + ew0 + mt * 16 + m];
        }
        COMPUTE_STEP(0, 0)
        __syncthreads();

        if (tt + 1 < 33) {
            const uint4* bs = (const uint4*)Bp + (size_t)(2 * tt + 2) * 1024;
#pragma unroll
            for (int r = 0; r < 4; r++) GLOAD_LDS16(bs + r * 256 + t, &Bl[0][r * 256 + t]);
        }
        COMPUTE_STEP(1, 2)
#pragma unroll
        for (int mt = 0; mt < 4; mt++) hfA[mt] = hfB[mt];
        __syncthreads();
    }
#undef COMPUTE_STEP

    // epilogue: C/D layout col=lane&15, row=q*4+reg
#pragma unroll
    for (int mt = 0; mt < 4; mt++) {
        int eb = ew0 + mt * 16 + q * 4;
#pragma unroll
        for (int r = 0; r < 4; r++) {
            int e = eb + r;
            if (e < NE) {
                int d = dstI[e];
                float* ap = aggr + (size_t)d * 64 + m;
                atomicAdd(ap + 0,  acc[mt][0][r]);
                atomicAdd(ap + 16, acc[mt][1][r]);
                atomicAdd(ap + 32, acc[mt][2][r]);
                atomicAdd(ap + 48, acc[mt][3][r]);
            }
        }
    }
}

// MFMA NNConv-root + GRU combine. Block=256 (4 waves), 64 nodes/block.
// Reads aggr AND zeroes it (owner thread only) -> removes per-step zero launch.
__global__ __launch_bounds__(256) void k_combine2(
        float* __restrict__ s, _Float16* __restrict__ s16,
        float* __restrict__ aggr, const float* __restrict__ deg,
        const _Float16* __restrict__ Bw, const float* __restrict__ cb,
        const float* __restrict__ bi, const float* __restrict__ bh) {
    __shared__ _Float16 ml[4][16][72];
    int t = threadIdx.x, w = t >> 6, lane = t & 63;
    int m = lane & 15, q = lane >> 4;
    int nb = blockIdx.x * 64 + w * 16;

    h8 sa0, sa1;
    {
        int node = nb + m; if (node >= NN) node = NN - 1;
        const _Float16* sp = s16 + (size_t)node * 64;
        sa0 = *(const h8*)(sp + q * 8);
        sa1 = *(const h8*)(sp + 32 + q * 8);
    }
    const h8* BW = (const h8*)Bw;

    f4 X[4], GH[12];
#pragma unroll
    for (int nt = 0; nt < 4; nt++) {
        X[nt] = (f4){0.f, 0.f, 0.f, 0.f};
        X[nt] = __builtin_amdgcn_mfma_f32_16x16x32_f16(sa0, BW[(nt * 2 + 0) * 64 + lane], X[nt], 0, 0, 0);
        X[nt] = __builtin_amdgcn_mfma_f32_16x16x32_f16(sa1, BW[(nt * 2 + 1) * 64 + lane], X[nt], 0, 0, 0);
    }
#pragma unroll
    for (int nt = 0; nt < 12; nt++) {
        GH[nt] = (f4){0.f, 0.f, 0.f, 0.f};
        GH[nt] = __builtin_amdgcn_mfma_f32_16x16x32_f16(sa0, BW[(32 + nt * 2 + 0) * 64 + lane], GH[nt], 0, 0, 0);
        GH[nt] = __builtin_amdgcn_mfma_f32_16x16x32_f16(sa1, BW[(32 + nt * 2 + 1) * 64 + lane], GH[nt], 0, 0, 0);
    }
#pragma unroll
    for (int r = 0; r < 4; r++) {
        int node = nb + q * 4 + r;
        bool ok = node < NN;
        int nc = ok ? node : NN - 1;
        float dn = fmaxf(deg[nc], 1.0f);
#pragma unroll
        for (int nt = 0; nt < 4; nt++) {
            int o = nt * 16 + m;
            size_t ai = (size_t)nc * 64 + o;
            float av = aggr[ai];
            if (ok) aggr[ai] = 0.0f;   // only the owning thread zeroes (no race)
            float mv = X[nt][r] + av / dn + cb[o];
            ml[w][q * 4 + r][o] = (_Float16)fmaxf(mv, 0.0f);
        }
    }
    __syncthreads();
    h8 ma0 = *(const h8*)&ml[w][m][q * 8];
    h8 ma1 = *(const h8*)&ml[w][m][32 + q * 8];

    f4 GI[12];
#pragma unroll
    for (int nt = 0; nt < 12; nt++) {
        GI[nt] = (f4){0.f, 0.f, 0.f, 0.f};
        GI[nt] = __builtin_amdgcn_mfma_f32_16x16x32_f16(ma0, BW[(8 + nt * 2 + 0) * 64 + lane], GI[nt], 0, 0, 0);
        GI[nt] = __builtin_amdgcn_mfma_f32_16x16x32_f16(ma1, BW[(8 + nt * 2 + 1) * 64 + lane], GI[nt], 0, 0, 0);
    }
#pragma unroll
    for (int og = 0; og < 4; og++) {
        int o = og * 16 + m;
        float bir = bi[o],       bhr = bh[o];
        float biz = bi[64 + o],  bhz = bh[64 + o];
        float bin = bi[128 + o], bhn = bh[128 + o];
#pragma unroll
        for (int r = 0; r < 4; r++) {
            int node = nb + q * 4 + r;
            if (node >= NN) continue;
            float rr = sigf(GI[og][r] + bir + GH[og][r] + bhr);
            float zz = sigf(GI[4 + og][r] + biz + GH[4 + og][r] + bhz);
            float ng = tanhf(GI[8 + og][r] + bin + rr * (GH[8 + og][r] + bhn));
            float hold = s[(size_t)node * 64 + o];
            float hnew = (1.0f - zz) * ng + zz * hold;
            s[(size_t)node * 64 + o] = hnew;
            s16[(size_t)node * 64 + o] = (_Float16)hnew;
        }
    }
}

// Set2Set v2: GPB=4 graphs per block (grid 625). Wave w owns graph g0+w.
// Gate matmul shares each weight load across 4 graphs; s rows staged in LDS
// once; pooling lane-per-node with butterfly max/sum + online-softmax merge.
__global__ __launch_bounds__(256) void k_s2s5(
        const float* __restrict__ LiT, const float* __restrict__ LhT,
        const float* __restrict__ bi, const float* __restrict__ bh,
        const float* __restrict__ s, const int* __restrict__ gstart,
        float* __restrict__ e_v,
        const float* __restrict__ w1, const float* __restrict__ b1,
        const float* __restrict__ w2, const float* __restrict__ b2,
        float* __restrict__ y) {
    __shared__ float sl[SCAP][65];
    __shared__ float qs[GPB][128], hv[GPB][64], cv[GPB][64], gg[GPB][256];
    __shared__ int ginfo[GPB + 1];
    int t = threadIdx.x, w = t >> 6, o = t & 63;
    int g0 = blockIdx.x * GPB;
    if (t <= GPB) ginfo[t] = gstart[g0 + t];
    if (t < 128) {
#pragma unroll
        for (int gr = 0; gr < GPB; gr++) qs[gr][t] = 0.0f;
    }
    if (t < 64) {
#pragma unroll
        for (int gr = 0; gr < GPB; gr++) { hv[gr][t] = 0.0f; cv[gr][t] = 0.0f; }
    }
    __syncthreads();
    int n00 = ginfo[0];
    int cnt4 = ginfo[GPB] - n00;
    bool staged = (cnt4 <= SCAP);
    if (staged) {
        for (int idx = t; idx < cnt4 * 16; idx += 256) {
            int node = idx >> 4, c4 = (idx & 15) * 4;
            float4 v = *(const float4*)&s[(size_t)(n00 + node) * 64 + c4];
            sl[node][c4 + 0] = v.x; sl[node][c4 + 1] = v.y;
            sl[node][c4 + 2] = v.z; sl[node][c4 + 3] = v.w;
        }
    }
    __syncthreads();
    int myn0 = ginfo[w] - n00, myn1 = ginfo[w + 1] - n00;

    for (int it = 0; it < 5; it++) {
        float a0 = bi[t] + bh[t], a1 = a0, a2 = a0, a3 = a0;
        for (int k = 0; k < 128; k++) {
            float wv = LiT[k * 256 + t];
            a0 += qs[0][k] * wv; a1 += qs[1][k] * wv;
            a2 += qs[2][k] * wv; a3 += qs[3][k] * wv;
        }
        for (int k = 0; k < 64; k++) {
            float wv = LhT[k * 256 + t];
            a0 += hv[0][k] * wv; a1 += hv[1][k] * wv;
            a2 += hv[2][k] * wv; a3 += hv[3][k] * wv;
        }
        gg[0][t] = a0; gg[1][t] = a1; gg[2][t] = a2; gg[3][t] = a3;
        __syncthreads();
        {
            float c_new = sigf(gg[w][64 + o]) * cv[w][o] + sigf(gg[w][o]) * tanhf(gg[w][128 + o]);
            cv[w][o] = c_new;
            float hq = sigf(gg[w][192 + o]) * tanhf(c_new);
            hv[w][o] = hq;
            qs[w][o] = hq;
            float m = -3.4e38f, l = 0.0f, r = 0.0f;
            if (staged) {
                for (int c0 = myn0; c0 < myn1; c0 += 64) {
                    int nn = myn1 - c0; if (nn > 64) nn = 64;
                    float e = -3.4e38f;
                    if (o < nn) {
                        const float* row = &sl[c0 + o][0];
                        float acc = 0.0f;
                        for (int k = 0; k < 64; k++) acc += row[k] * qs[w][k];
                        e = acc;
                    }
                    float cm = e;
#pragma unroll
                    for (int off = 32; off; off >>= 1) cm = fmaxf(cm, __shfl_xor(cm, off, 64));
                    float mn = fmaxf(m, cm);
                    float a = (o < nn) ? __expf(e - mn) : 0.0f;
                    float csum = a;
#pragma unroll
                    for (int off = 32; off; off >>= 1) csum += __shfl_xor(csum, off, 64);
                    float scale = (m > -3.0e38f) ? __expf(m - mn) : 0.0f;
                    l = l * scale + csum;
                    r = r * scale;
                    for (int j = 0; j < nn; j++) {
                        float aj = __shfl(a, j, 64);
                        r += aj * sl[c0 + j][o];
                    }
                    m = mn;
                }
            } else {
                int an0 = myn0 + n00, an1 = myn1 + n00;
                float mx = -3.4e38f;
                for (int n = an0; n < an1; n++) {
                    float v = s[(size_t)n * 64 + o] * hq;
#pragma unroll
                    for (int off = 32; off; off >>= 1) v += __shfl_xor(v, off, 64);
                    if (o == 0) e_v[n] = v;
                    mx = fmaxf(mx, v);
                }
                float asum = 0.0f, rp = 0.0f;
                for (int n = an0; n < an1; n++) {
                    float a = __expf(e_v[n] - mx);
                    asum += a;
                    rp += a * s[(size_t)n * 64 + o];
                }
                l = asum; r = rp;
            }
            qs[w][64 + o] = r / (l + 1e-16f);
        }
        __syncthreads();
    }

    {
        float acc = b1[o];
        for (int k = 0; k < 128; k++) acc += qs[w][k] * w1[k * 64 + o];
        float hid = fmaxf(acc, 0.0f) * w2[o];
#pragma unroll
        for (int off = 32; off; off >>= 1) hid += __shfl_down(hid, off, 64);
        if (o == 0) y[g0 + w] = hid + b2[0];
    }
}

extern "C" void kernel_launch(void* const* d_in, const int* in_sizes, int n_in,
                              void* d_out, int out_size, void* d_ws, size_t ws_size,
                              hipStream_t stream) {
    const float* x       = (const float*)d_in[0];
    const float* z       = (const float*)d_in[1];
    const float* ea      = (const float*)d_in[2];
    const float* lin0_w  = (const float*)d_in[3];
    const float* lin0_b  = (const float*)d_in[4];
    const float* emlp_w1 = (const float*)d_in[5];
    const float* emlp_b1 = (const float*)d_in[6];
    const float* emlp_w2 = (const float*)d_in[7];
    const float* emlp_b2 = (const float*)d_in[8];
    const float* conv_r  = (const float*)d_in[9];
    const float* conv_b  = (const float*)d_in[10];
    const float* gru_wi  = (const float*)d_in[11];
    const float* gru_wh  = (const float*)d_in[12];
    const float* gru_bi  = (const float*)d_in[13];
    const float* gru_bh  = (const float*)d_in[14];
    const float* lstm_wi = (const float*)d_in[15];
    const float* lstm_wh = (const float*)d_in[16];
    const float* lstm_bi = (const float*)d_in[17];
    const float* lstm_bh = (const float*)d_in[18];
    const float* lin1_w  = (const float*)d_in[19];
    const float* lin1_b  = (const float*)d_in[20];
    const float* lin2_w  = (const float*)d_in[21];
    const float* lin2_b  = (const float*)d_in[22];
    const int* eidx      = (const int*)d_in[23];
    const int* batch     = (const int*)d_in[24];
    const int* srcI = eidx;
    const int* dstI = eidx + NE;
    float* y = (float*)d_out;

    char* w = (char*)d_ws;
    size_t off = 0;
    auto alloc = [&](size_t bytes) -> void* {
        void* p = w + off;
        off += (bytes + 255) & ~(size_t)255;
        return p;
    };
    float* s      = (float*)alloc((size_t)NN * 64 * 4);
    float* aggr   = (float*)alloc((size_t)NN * 64 * 4);  // NN*64*4 is 256-aligned ->
    float* deg    = (float*)alloc((size_t)NN * 4);       // deg is contiguous after aggr
    float* e_v    = (float*)alloc((size_t)NN * 4);
    float* LiT    = (float*)alloc(256 * 128 * 4);
    float* LhT    = (float*)alloc(256 * 64 * 4);
    int*   gstart = (int*)alloc((size_t)(NG + 1) * 4);
    _Float16* s16 = (_Float16*)alloc((size_t)NN * 64 * 2);
    _Float16* hidT= (_Float16*)alloc((size_t)34 * EPAD * 4 * 2);  // 33 groups + 1 slack
    _Float16* Bp  = (_Float16*)alloc((size_t)KCH * 4 * 64 * 8 * 2);
    _Float16* Bw  = (_Float16*)alloc((size_t)56 * 64 * 8 * 2);
    (void)ws_size;  // ~60 MB total, well under proven capacity

    // mega-prologue: lin0+f16, edge-MLP->hidT4, prep_B, prep_W, LSTM transposes,
    // gstart, zero(aggr|deg) — all independent, one dispatch
    int nb_pro = NBL0 + NBEM + NBPB + NBPW + NBT1 + NBT2 + NBGS + NBZ;
    k_prologue<<<nb_pro, 256, 0, stream>>>(
        x, z, lin0_w, lin0_b, s, s16,
        ea, emlp_w1, emlp_b1, hidT,
        emlp_w2, emlp_b2, Bp,
        conv_r, gru_wi, gru_wh, Bw,
        lstm_wi, lstm_wh, LiT, LhT,
        batch, gstart, (float4*)aggr);
    k_deg<<<(NE + 255) / 256, 256, 0, stream>>>(dstI, deg);

    // 5 message-passing + GRU steps (k_fused: 391 blocks x 256 thr)
    for (int step = 0; step < 5; step++) {
        k_fused<<<EPAD / 256, 256, 0, stream>>>(s16, hidT, Bp, srcI, dstI, aggr);
        k_combine2<<<(NN + 63) / 64, 256, 0, stream>>>(s, s16, aggr, deg, Bw,
                                                       conv_b, gru_bi, gru_bh);
    }

    // Set2Set (5 iterations, 4 graphs/block) + output head: one launch
    k_s2s5<<<NG / GPB, 256, 0, stream>>>(LiT, LhT, lstm_bi, lstm_bh, s, gstart, e_v,
                                         lin1_w, lin1_b, lin2_w, lin2_b, y);
}

// Round 13
// 882.809 us; speedup vs baseline: 1.0726x; 1.0019x over previous
//
#include <hip/hip_runtime.h>
#include <hip/hip_bf16.h>

#define NN 50000      // nodes
#define NE 100000     // edges
#define NG 2500       // graphs
#define WW 128        // edge-mlp width
#define EPAD 100096   // 391 blocks * 256 edges (= 782 * 128)
#define KCH 264       // K chunks of 32: 8448 = 132 h-rows * 64 (128 hid + 1 bias + 3 zero)
#define GPB 4         // graphs per s2s block
#define SCAP 160      // max staged nodes per s2s block (4 graphs, avg 80)

// mega-prologue block partition (cumulative ranges)
#define NBL0 3125     // lin0: NN*64/256/4 (grid-stride x4)
#define NBEM 1564     // emlp_t: EPAD/64
#define NBPB 264      // prep_B: KCH*4*64/256
#define NBPW 14       // prep_W
#define NBT1 128      // transpose LiT: 256*128/256
#define NBT2 64       // transpose LhT: 256*64/256
#define NBGS 196      // gstart: ceil((NN+1)/256)
#define NBZ  794      // zero aggr+deg: ceil(NN*65/4/256/4) (grid-stride x4)

typedef _Float16 h8 __attribute__((ext_vector_type(8)));
typedef _Float16 h4 __attribute__((ext_vector_type(4)));
typedef float    f4 __attribute__((ext_vector_type(4)));

#define GLOAD_LDS16(g, l) __builtin_amdgcn_global_load_lds( \
    (const __attribute__((address_space(1))) void*)(g),     \
    (__attribute__((address_space(3))) void*)(l), 16, 0, 0)

__device__ __forceinline__ float sigf(float x) { return 1.0f / (1.0f + __expf(-x)); }

// ---- mega-prologue: lin0 | emlp_t | prep_B | prep_W | transposes | gstart | zero
__global__ __launch_bounds__(256) void k_prologue(
        const float* __restrict__ x, const float* __restrict__ z,
        const float* __restrict__ lin0_w, const float* __restrict__ lin0_b,
        float* __restrict__ s, _Float16* __restrict__ s16,
        const float* __restrict__ ea, const float* __restrict__ w1,
        const float* __restrict__ b1, _Float16* __restrict__ hidT4,
        const float* __restrict__ w2, const float* __restrict__ b2,
        _Float16* __restrict__ Bp,
        const float* __restrict__ conv_root, const float* __restrict__ gru_wi,
        const float* __restrict__ gru_wh, _Float16* __restrict__ Bw,
        const float* __restrict__ lstm_wi, const float* __restrict__ lstm_wh,
        float* __restrict__ LiT, float* __restrict__ LhT,
        const int* __restrict__ batch, int* __restrict__ gstart,
        float4* __restrict__ zbase) {
    __shared__ _Float16 hl[132][64];
    int bx = blockIdx.x, t = threadIdx.x;

    if (bx < NBL0) {
        // ---- lin0 (x4 grid-stride): s[n,o] = relu([x|z]@lin0_w + b), + f16 copy
#pragma unroll
        for (int rep = 0; rep < 4; rep++) {
            int idx = (bx * 4 + rep) * 256 + t;   // covers NN*64 exactly
            int n = idx >> 6, o = idx & 63;
            float acc = lin0_b[o];
#pragma unroll
            for (int i = 0; i < 15; i++) acc += x[n * 15 + i] * lin0_w[i * 64 + o];
            acc += z[n] * lin0_w[15 * 64 + o];
            float r = fmaxf(acc, 0.0f);
            s[idx] = r;
            s16[idx] = (_Float16)r;
        }
        return;
    }
    bx -= NBL0;
    if (bx < NBEM) {
        // ---- edge MLP layer 1 + repack to h4 groups
        int e0 = bx * 64;
        int e_l = t & 63, w = t >> 6;
        int e = e0 + e_l;
        float a0 = 0, a1 = 0, a2 = 0, a3 = 0, a4 = 0;
        if (e < NE) {
            a0 = ea[e * 5 + 0]; a1 = ea[e * 5 + 1]; a2 = ea[e * 5 + 2];
            a3 = ea[e * 5 + 3]; a4 = ea[e * 5 + 4];
        }
        for (int h = w * 32; h < w * 32 + 32; h++) {
            float acc = b1[h];
            acc += a0 * w1[0 * 128 + h] + a1 * w1[1 * 128 + h] + a2 * w1[2 * 128 + h]
                 + a3 * w1[3 * 128 + h] + a4 * w1[4 * 128 + h];
            hl[h][e_l] = (_Float16)fmaxf(acc, 0.0f);
        }
        if (t < 64) hl[128][t] = (_Float16)1.0f;
        else if (t < 128) hl[129][t - 64] = (_Float16)0.0f;
        else if (t < 192) hl[130][t - 128] = (_Float16)0.0f;
        else hl[131][t - 192] = (_Float16)0.0f;
        __syncthreads();
#pragma unroll
        for (int it = 0; it < 9; it++) {
            int hq = it * 4 + w;
            if (hq < 33) {
                h4 v = { hl[hq * 4 + 0][e_l], hl[hq * 4 + 1][e_l],
                         hl[hq * 4 + 2][e_l], hl[hq * 4 + 3][e_l] };
                *(h4*)(hidT4 + ((size_t)hq * EPAD + e0 + e_l) * 4) = v;
            }
        }
        return;
    }
    bx -= NBEM;
    if (bx < NBPB) {
        // ---- prep_B: [w2 ; b2 ; 0] into MFMA-fragment order
        int g = bx * 256 + t;
        int l = g & 63, tt = (g >> 6) & 3, c = g >> 8;
        int n = tt * 16 + (l & 15);
        int kb = c * 32 + (l >> 4) * 8;
        h8 v;
#pragma unroll
        for (int j = 0; j < 8; j++) {
            int k = kb + j;
            float f = 0.0f;
            if (k < 8192) f = w2[(size_t)k * 64 + n];
            else if (k < 8256) f = b2[(k - 8192) * 64 + n];
            v[j] = (_Float16)f;
        }
        *((h8*)Bp + g) = v;
        return;
    }
    bx -= NBPB;
    if (bx < NBPW) {
        // ---- prep_W: combine weights into MFMA B-fragment layout
        int g = bx * 256 + t;
        if (g >= 56 * 64) return;
        int l = g & 63, unit = g >> 6;
        int kb = ((unit & 1) * 32) + (l >> 4) * 8;
        h8 v;
        if (unit < 8) {
            int nt = unit >> 1;
            int n = nt * 16 + (l & 15);
#pragma unroll
            for (int j = 0; j < 8; j++) v[j] = (_Float16)conv_root[(kb + j) * 64 + n];
        } else if (unit < 32) {
            int nt = (unit - 8) >> 1;
            int o = nt * 16 + (l & 15);
#pragma unroll
            for (int j = 0; j < 8; j++) v[j] = (_Float16)gru_wi[o * 64 + kb + j];
        } else {
            int nt = (unit - 32) >> 1;
            int o = nt * 16 + (l & 15);
#pragma unroll
            for (int j = 0; j < 8; j++) v[j] = (_Float16)gru_wh[o * 64 + kb + j];
        }
        *((h8*)Bw + g) = v;
        return;
    }
    bx -= NBPW;
    if (bx < NBT1) {
        // ---- LiT[c*256+r] = lstm_wi[r*128+c]
        int idx = bx * 256 + t;
        int r = idx / 128, c = idx % 128;
        LiT[c * 256 + r] = lstm_wi[idx];
        return;
    }
    bx -= NBT1;
    if (bx < NBT2) {
        // ---- LhT[c*256+r] = lstm_wh[r*64+c]
        int idx = bx * 256 + t;
        int r = idx / 64, c = idx % 64;
        LhT[c * 256 + r] = lstm_wh[idx];
        return;
    }
    bx -= NBT2;
    if (bx < NBGS) {
        // ---- gstart
        int n = bx * 256 + t;
        if (n > NN) return;
        int b1v = (n < NN) ? batch[n] : NG;
        int b0v = (n == 0) ? -1 : batch[n - 1];
        for (int g = b0v + 1; g <= b1v; g++) gstart[g] = n;
        return;
    }
    bx -= NBGS;
    {
        // ---- zero aggr+deg (x4 grid-stride; contiguous NN*65 floats)
#pragma unroll
        for (int rep = 0; rep < 4; rep++) {
            int i = (bx * 4 + rep) * 256 + t;
            if (i < (NN * 65 / 4)) zbase[i] = make_float4(0.f, 0.f, 0.f, 0.f);
        }
    }
}

// Fused NNConv message (v6 config — best measured across 5 geometry variants:
// 108.5-110 us, ~990 TF = the plain-HIP 2-barrier structural ceiling).
// 256 edges/block share one LDS-staged B stream; K-step 128 double-buffered;
// stage-before-compute. do_deg=1 (step 0 only): also accumulates in-degree
// (391*256 threads >= NE, 1 atomicAdd each, hidden under the K-loop; deg is
// first read by combine2 AFTER this dispatch completes).
__global__ __launch_bounds__(256, 3) void k_fused(
        const _Float16* __restrict__ s16, const _Float16* __restrict__ hidT4,
        const _Float16* __restrict__ Bp, const int* __restrict__ srcI,
        const int* __restrict__ dstI, float* __restrict__ aggr,
        int do_deg, float* __restrict__ deg) {
    __shared__ uint4 Bl[2][1024];         // 2 x 16 KB (K-step 128)
    int t = threadIdx.x, w = t >> 6, lane = t & 63;
    int m = lane & 15, q = lane >> 4;
    int ew0 = blockIdx.x * 256 + w * 64;  // wave's 64 edges

    if (do_deg) {
        int e = blockIdx.x * 256 + t;
        if (e < NE) atomicAdd(&deg[dstI[e]], 1.0f);
    }

    h8 sA[4][2];
#pragma unroll
    for (int mt = 0; mt < 4; mt++) {
        int e = ew0 + mt * 16 + m;
        int src = (e < NE) ? srcI[e] : 0;
        const _Float16* sp = s16 + (size_t)src * 64;
        sA[mt][0] = *(const h8*)(sp + q * 8);
        sA[mt][1] = *(const h8*)(sp + 32 + q * 8);
    }
    f4 acc[4][4];
#pragma unroll
    for (int mt = 0; mt < 4; mt++)
#pragma unroll
        for (int nt = 0; nt < 4; nt++) acc[mt][nt] = (f4){0.f, 0.f, 0.f, 0.f};

    const h4* hT = (const h4*)hidT4;
    h4 hfA[4], hfB[4];
#pragma unroll
    for (int mt = 0; mt < 4; mt++)
        hfA[mt] = hT[(size_t)0 * EPAD + ew0 + mt * 16 + m];

    {
        const uint4* bs = (const uint4*)Bp;
#pragma unroll
        for (int r = 0; r < 4; r++) GLOAD_LDS16(bs + r * 256 + t, &Bl[0][r * 256 + t]);
    }
    __syncthreads();

#define COMPUTE_STEP(BUF, HH)                                                  \
    _Pragma("unroll")                                                          \
    for (int c2 = 0; c2 < 4; c2++) {                                           \
        h8 b0 = *(const h8*)&Bl[BUF][(c2 * 4 + 0) * 64 + lane];                \
        h8 b1 = *(const h8*)&Bl[BUF][(c2 * 4 + 1) * 64 + lane];                \
        h8 b2 = *(const h8*)&Bl[BUF][(c2 * 4 + 2) * 64 + lane];                \
        h8 b3 = *(const h8*)&Bl[BUF][(c2 * 4 + 3) * 64 + lane];                \
        _Pragma("unroll")                                                      \
        for (int mt = 0; mt < 4; mt++) {                                       \
            h8 a = sA[mt][c2 & 1] * hfA[mt][(HH) + (c2 >> 1)];                 \
            acc[mt][0] = __builtin_amdgcn_mfma_f32_16x16x32_f16(a, b0, acc[mt][0], 0, 0, 0); \
            acc[mt][1] = __builtin_amdgcn_mfma_f32_16x16x32_f16(a, b1, acc[mt][1], 0, 0, 0); \
            acc[mt][2] = __builtin_amdgcn_mfma_f32_16x16x32_f16(a, b2, acc[mt][2], 0, 0, 0); \
            acc[mt][3] = __builtin_amdgcn_mfma_f32_16x16x32_f16(a, b3, acc[mt][3], 0, 0, 0); \
        }                                                                      \
    }

    for (int tt = 0; tt < 33; tt++) {
        {
            const uint4* bs = (const uint4*)Bp + (size_t)(2 * tt + 1) * 1024;
#pragma unroll
            for (int r = 0; r < 4; r++) GLOAD_LDS16(bs + r * 256 + t, &Bl[1][r * 256 + t]);
        }
        {
#pragma unroll
            for (int mt = 0; mt < 4; mt++)
                hfB[mt] = hT[(size_t)(tt + 1) * EPAD + ew0 + mt * 16 + m];
        }
        COMPUTE_STEP(0, 0)
        __syncthreads();

        if (tt + 1 < 33) {
            const uint4* bs = (const uint4*)Bp + (size_t)(2 * tt + 2) * 1024;
#pragma unroll
            for (int r = 0; r < 4; r++) GLOAD_LDS16(bs + r * 256 + t, &Bl[0][r * 256 + t]);
        }
        COMPUTE_STEP(1, 2)
#pragma unroll
        for (int mt = 0; mt < 4; mt++) hfA[mt] = hfB[mt];
        __syncthreads();
    }
#undef COMPUTE_STEP

    // epilogue: C/D layout col=lane&15, row=q*4+reg
#pragma unroll
    for (int mt = 0; mt < 4; mt++) {
        int eb = ew0 + mt * 16 + q * 4;
#pragma unroll
        for (int r = 0; r < 4; r++) {
            int e = eb + r;
            if (e < NE) {
                int d = dstI[e];
                float* ap = aggr + (size_t)d * 64 + m;
                atomicAdd(ap + 0,  acc[mt][0][r]);
                atomicAdd(ap + 16, acc[mt][1][r]);
                atomicAdd(ap + 32, acc[mt][2][r]);
                atomicAdd(ap + 48, acc[mt][3][r]);
            }
        }
    }
}

// MFMA NNConv-root + GRU combine. Block=256 (4 waves), 64 nodes/block.
// Reads aggr AND zeroes it (owner thread only).
__global__ __launch_bounds__(256) void k_combine2(
        float* __restrict__ s, _Float16* __restrict__ s16,
        float* __restrict__ aggr, const float* __restrict__ deg,
        const _Float16* __restrict__ Bw, const float* __restrict__ cb,
        const float* __restrict__ bi, const float* __restrict__ bh) {
    __shared__ _Float16 ml[4][16][72];
    int t = threadIdx.x, w = t >> 6, lane = t & 63;
    int m = lane & 15, q = lane >> 4;
    int nb = blockIdx.x * 64 + w * 16;

    h8 sa0, sa1;
    {
        int node = nb + m; if (node >= NN) node = NN - 1;
        const _Float16* sp = s16 + (size_t)node * 64;
        sa0 = *(const h8*)(sp + q * 8);
        sa1 = *(const h8*)(sp + 32 + q * 8);
    }
    const h8* BW = (const h8*)Bw;

    f4 X[4], GH[12];
#pragma unroll
    for (int nt = 0; nt < 4; nt++) {
        X[nt] = (f4){0.f, 0.f, 0.f, 0.f};
        X[nt] = __builtin_amdgcn_mfma_f32_16x16x32_f16(sa0, BW[(nt * 2 + 0) * 64 + lane], X[nt], 0, 0, 0);
        X[nt] = __builtin_amdgcn_mfma_f32_16x16x32_f16(sa1, BW[(nt * 2 + 1) * 64 + lane], X[nt], 0, 0, 0);
    }
#pragma unroll
    for (int nt = 0; nt < 12; nt++) {
        GH[nt] = (f4){0.f, 0.f, 0.f, 0.f};
        GH[nt] = __builtin_amdgcn_mfma_f32_16x16x32_f16(sa0, BW[(32 + nt * 2 + 0) * 64 + lane], GH[nt], 0, 0, 0);
        GH[nt] = __builtin_amdgcn_mfma_f32_16x16x32_f16(sa1, BW[(32 + nt * 2 + 1) * 64 + lane], GH[nt], 0, 0, 0);
    }
#pragma unroll
    for (int r = 0; r < 4; r++) {
        int node = nb + q * 4 + r;
        bool ok = node < NN;
        int nc = ok ? node : NN - 1;
        float dn = fmaxf(deg[nc], 1.0f);
#pragma unroll
        for (int nt = 0; nt < 4; nt++) {
            int o = nt * 16 + m;
            size_t ai = (size_t)nc * 64 + o;
            float av = aggr[ai];
            if (ok) aggr[ai] = 0.0f;   // only the owning thread zeroes (no race)
            float mv = X[nt][r] + av / dn + cb[o];
            ml[w][q * 4 + r][o] = (_Float16)fmaxf(mv, 0.0f);
        }
    }
    __syncthreads();
    h8 ma0 = *(const h8*)&ml[w][m][q * 8];
    h8 ma1 = *(const h8*)&ml[w][m][32 + q * 8];

    f4 GI[12];
#pragma unroll
    for (int nt = 0; nt < 12; nt++) {
        GI[nt] = (f4){0.f, 0.f, 0.f, 0.f};
        GI[nt] = __builtin_amdgcn_mfma_f32_16x16x32_f16(ma0, BW[(8 + nt * 2 + 0) * 64 + lane], GI[nt], 0, 0, 0);
        GI[nt] = __builtin_amdgcn_mfma_f32_16x16x32_f16(ma1, BW[(8 + nt * 2 + 1) * 64 + lane], GI[nt], 0, 0, 0);
    }
#pragma unroll
    for (int og = 0; og < 4; og++) {
        int o = og * 16 + m;
        float bir = bi[o],       bhr = bh[o];
        float biz = bi[64 + o],  bhz = bh[64 + o];
        float bin = bi[128 + o], bhn = bh[128 + o];
#pragma unroll
        for (int r = 0; r < 4; r++) {
            int node = nb + q * 4 + r;
            if (node >= NN) continue;
            float rr = sigf(GI[og][r] + bir + GH[og][r] + bhr);
            float zz = sigf(GI[4 + og][r] + biz + GH[4 + og][r] + bhz);
            float ng = tanhf(GI[8 + og][r] + bin + rr * (GH[8 + og][r] + bhn));
            float hold = s[(size_t)node * 64 + o];
            float hnew = (1.0f - zz) * ng + zz * hold;
            s[(size_t)node * 64 + o] = hnew;
            s16[(size_t)node * 64 + o] = (_Float16)hnew;
        }
    }
}

// Set2Set v2: GPB=4 graphs per block (grid 625). Wave w owns graph g0+w.
__global__ __launch_bounds__(256) void k_s2s5(
        const float* __restrict__ LiT, const float* __restrict__ LhT,
        const float* __restrict__ bi, const float* __restrict__ bh,
        const float* __restrict__ s, const int* __restrict__ gstart,
        float* __restrict__ e_v,
        const float* __restrict__ w1, const float* __restrict__ b1,
        const float* __restrict__ w2, const float* __restrict__ b2,
        float* __restrict__ y) {
    __shared__ float sl[SCAP][65];
    __shared__ float qs[GPB][128], hv[GPB][64], cv[GPB][64], gg[GPB][256];
    __shared__ int ginfo[GPB + 1];
    int t = threadIdx.x, w = t >> 6, o = t & 63;
    int g0 = blockIdx.x * GPB;
    if (t <= GPB) ginfo[t] = gstart[g0 + t];
    if (t < 128) {
#pragma unroll
        for (int gr = 0; gr < GPB; gr++) qs[gr][t] = 0.0f;
    }
    if (t < 64) {
#pragma unroll
        for (int gr = 0; gr < GPB; gr++) { hv[gr][t] = 0.0f; cv[gr][t] = 0.0f; }
    }
    __syncthreads();
    int n00 = ginfo[0];
    int cnt4 = ginfo[GPB] - n00;
    bool staged = (cnt4 <= SCAP);
    if (staged) {
        for (int idx = t; idx < cnt4 * 16; idx += 256) {
            int node = idx >> 4, c4 = (idx & 15) * 4;
            float4 v = *(const float4*)&s[(size_t)(n00 + node) * 64 + c4];
            sl[node][c4 + 0] = v.x; sl[node][c4 + 1] = v.y;
            sl[node][c4 + 2] = v.z; sl[node][c4 + 3] = v.w;
        }
    }
    __syncthreads();
    int myn0 = ginfo[w] - n00, myn1 = ginfo[w + 1] - n00;

    for (int it = 0; it < 5; it++) {
        float a0 = bi[t] + bh[t], a1 = a0, a2 = a0, a3 = a0;
        for (int k = 0; k < 128; k++) {
            float wv = LiT[k * 256 + t];
            a0 += qs[0][k] * wv; a1 += qs[1][k] * wv;
            a2 += qs[2][k] * wv; a3 += qs[3][k] * wv;
        }
        for (int k = 0; k < 64; k++) {
            float wv = LhT[k * 256 + t];
            a0 += hv[0][k] * wv; a1 += hv[1][k] * wv;
            a2 += hv[2][k] * wv; a3 += hv[3][k] * wv;
        }
        gg[0][t] = a0; gg[1][t] = a1; gg[2][t] = a2; gg[3][t] = a3;
        __syncthreads();
        {
            float c_new = sigf(gg[w][64 + o]) * cv[w][o] + sigf(gg[w][o]) * tanhf(gg[w][128 + o]);
            cv[w][o] = c_new;
            float hq = sigf(gg[w][192 + o]) * tanhf(c_new);
            hv[w][o] = hq;
            qs[w][o] = hq;
            float m = -3.4e38f, l = 0.0f, r = 0.0f;
            if (staged) {
                for (int c0 = myn0; c0 < myn1; c0 += 64) {
                    int nn = myn1 - c0; if (nn > 64) nn = 64;
                    float e = -3.4e38f;
                    if (o < nn) {
                        const float* row = &sl[c0 + o][0];
                        float acc = 0.0f;
                        for (int k = 0; k < 64; k++) acc += row[k] * qs[w][k];
                        e = acc;
                    }
                    float cm = e;
#pragma unroll
                    for (int off = 32; off; off >>= 1) cm = fmaxf(cm, __shfl_xor(cm, off, 64));
                    float mn = fmaxf(m, cm);
                    float a = (o < nn) ? __expf(e - mn) : 0.0f;
                    float csum = a;
#pragma unroll
                    for (int off = 32; off; off >>= 1) csum += __shfl_xor(csum, off, 64);
                    float scale = (m > -3.0e38f) ? __expf(m - mn) : 0.0f;
                    l = l * scale + csum;
                    r = r * scale;
                    for (int j = 0; j < nn; j++) {
                        float aj = __shfl(a, j, 64);
                        r += aj * sl[c0 + j][o];
                    }
                    m = mn;
                }
            } else {
                int an0 = myn0 + n00, an1 = myn1 + n00;
                float mx = -3.4e38f;
                for (int n = an0; n < an1; n++) {
                    float v = s[(size_t)n * 64 + o] * hq;
#pragma unroll
                    for (int off = 32; off; off >>= 1) v += __shfl_xor(v, off, 64);
                    if (o == 0) e_v[n] = v;
                    mx = fmaxf(mx, v);
                }
                float asum = 0.0f, rp = 0.0f;
                for (int n = an0; n < an1; n++) {
                    float a = __expf(e_v[n] - mx);
                    asum += a;
                    rp += a * s[(size_t)n * 64 + o];
                }
                l = asum; r = rp;
            }
            qs[w][64 + o] = r / (l + 1e-16f);
        }
        __syncthreads();
    }

    {
        float acc = b1[o];
        for (int k = 0; k < 128; k++) acc += qs[w][k] * w1[k * 64 + o];
        float hid = fmaxf(acc, 0.0f) * w2[o];
#pragma unroll
        for (int off = 32; off; off >>= 1) hid += __shfl_down(hid, off, 64);
        if (o == 0) y[g0 + w] = hid + b2[0];
    }
}

extern "C" void kernel_launch(void* const* d_in, const int* in_sizes, int n_in,
                              void* d_out, int out_size, void* d_ws, size_t ws_size,
                              hipStream_t stream) {
    const float* x       = (const float*)d_in[0];
    const float* z       = (const float*)d_in[1];
    const float* ea      = (const float*)d_in[2];
    const float* lin0_w  = (const float*)d_in[3];
    const float* lin0_b  = (const float*)d_in[4];
    const float* emlp_w1 = (const float*)d_in[5];
    const float* emlp_b1 = (const float*)d_in[6];
    const float* emlp_w2 = (const float*)d_in[7];
    const float* emlp_b2 = (const float*)d_in[8];
    const float* conv_r  = (const float*)d_in[9];
    const float* conv_b  = (const float*)d_in[10];
    const float* gru_wi  = (const float*)d_in[11];
    const float* gru_wh  = (const float*)d_in[12];
    const float* gru_bi  = (const float*)d_in[13];
    const float* gru_bh  = (const float*)d_in[14];
    const float* lstm_wi = (const float*)d_in[15];
    const float* lstm_wh = (const float*)d_in[16];
    const float* lstm_bi = (const float*)d_in[17];
    const float* lstm_bh = (const float*)d_in[18];
    const float* lin1_w  = (const float*)d_in[19];
    const float* lin1_b  = (const float*)d_in[20];
    const float* lin2_w  = (const float*)d_in[21];
    const float* lin2_b  = (const float*)d_in[22];
    const int* eidx      = (const int*)d_in[23];
    const int* batch     = (const int*)d_in[24];
    const int* srcI = eidx;
    const int* dstI = eidx + NE;
    float* y = (float*)d_out;

    char* w = (char*)d_ws;
    size_t off = 0;
    auto alloc = [&](size_t bytes) -> void* {
        void* p = w + off;
        off += (bytes + 255) & ~(size_t)255;
        return p;
    };
    float* s      = (float*)alloc((size_t)NN * 64 * 4);
    float* aggr   = (float*)alloc((size_t)NN * 64 * 4);  // NN*64*4 is 256-aligned ->
    float* deg    = (float*)alloc((size_t)NN * 4);       // deg is contiguous after aggr
    float* e_v    = (float*)alloc((size_t)NN * 4);
    float* LiT    = (float*)alloc(256 * 128 * 4);
    float* LhT    = (float*)alloc(256 * 64 * 4);
    int*   gstart = (int*)alloc((size_t)(NG + 1) * 4);
    _Float16* s16 = (_Float16*)alloc((size_t)NN * 64 * 2);
    _Float16* hidT= (_Float16*)alloc((size_t)34 * EPAD * 4 * 2);  // 33 groups + 1 slack
    _Float16* Bp  = (_Float16*)alloc((size_t)KCH * 4 * 64 * 8 * 2);
    _Float16* Bw  = (_Float16*)alloc((size_t)56 * 64 * 8 * 2);
    (void)ws_size;  // ~60 MB total, well under proven capacity

    // mega-prologue: lin0+f16, edge-MLP->hidT4, prep_B, prep_W, LSTM transposes,
    // gstart, zero(aggr|deg) — all independent, one dispatch
    int nb_pro = NBL0 + NBEM + NBPB + NBPW + NBT1 + NBT2 + NBGS + NBZ;
    k_prologue<<<nb_pro, 256, 0, stream>>>(
        x, z, lin0_w, lin0_b, s, s16,
        ea, emlp_w1, emlp_b1, hidT,
        emlp_w2, emlp_b2, Bp,
        conv_r, gru_wi, gru_wh, Bw,
        lstm_wi, lstm_wh, LiT, LhT,
        batch, gstart, (float4*)aggr);

    // 5 message-passing + GRU steps (step 0 also accumulates deg inside k_fused)
    for (int step = 0; step < 5; step++) {
        k_fused<<<EPAD / 256, 256, 0, stream>>>(s16, hidT, Bp, srcI, dstI, aggr,
                                                step == 0 ? 1 : 0, deg);
        k_combine2<<<(NN + 63) / 64, 256, 0, stream>>>(s, s16, aggr, deg, Bw,
                                                       conv_b, gru_bi, gru_bh);
    }

    // Set2Set (5 iterations, 4 graphs/block) + output head: one launch
    k_s2s5<<<NG / GPB, 256, 0, stream>>>(LiT, LhT, lstm_bi, lstm_bh, s, gstart, e_v,
                                         lin1_w, lin1_b, lin2_w, lin2_b, y);
}